// Round 11
// baseline (9099.863 us; speedup 1.0000x reference)
//
#include <hip/hip_runtime.h>
#include <stdint.h>
#include <stdio.h>

// Problem constants
#define TL 1024          // T
#define BB 64            // B
#define HH 512           // H
#define II 1024          // input size (== 2H for layer 2)
#define NL 2             // layers
#define BT_ (BB*TL)      // 65536
#define G3_ 1536         // 3H
#define N2_ 3072         // 2*3H (both dirs stacked)

typedef _Float16 h8 __attribute__((ext_vector_type(8)));
typedef _Float16 h4 __attribute__((ext_vector_type(4)));
typedef _Float16 h2 __attribute__((ext_vector_type(2)));
typedef float    f4 __attribute__((ext_vector_type(4)));
typedef unsigned int u4 __attribute__((ext_vector_type(4)));
typedef unsigned int u2v __attribute__((ext_vector_type(2)));

// ---------------- fp32 -> fp16 convert ----------------
__global__ void cvt_f2h(const float* __restrict__ src, _Float16* __restrict__ dst, size_t n4) {
  size_t i = (size_t)blockIdx.x*blockDim.x + threadIdx.x;
  size_t stride = (size_t)gridDim.x*blockDim.x;
  for (; i < n4; i += stride) {
    f4 v = ((const f4*)src)[i];
    h4 o;
    o[0] = (_Float16)v[0]; o[1] = (_Float16)v[1];
    o[2] = (_Float16)v[2]; o[3] = (_Float16)v[3];
    ((h4*)dst)[i] = o;
  }
}

// ---------------- gi GEMM (unchanged, proven) ----------------
#define LDA 40
__launch_bounds__(256)
__global__ void gemm_gi(const _Float16* __restrict__ A, const _Float16* __restrict__ Bw,
                        const float* __restrict__ bias, _Float16* __restrict__ gi)
{
  const int bn = blockIdx.x, bm = blockIdx.y;
  const int tid = threadIdx.x;
  const int wave = tid >> 6, lane = tid & 63;
  const int wm = wave >> 1, wn = wave & 1;
  const int lo = lane & 15, hi = lane >> 4;
  __shared__ _Float16 As[128*LDA];
  __shared__ _Float16 Bs[128*LDA];
  f4 acc[4][4] = {};
  const int r0 = tid >> 2, c0 = (tid & 3)*8;
  const _Float16* Ag = A + (size_t)(bm*128)*II;
  const _Float16* Bg = Bw + (size_t)(bn*128)*II;
  u4 a0 = *(const u4*)(Ag + (size_t)r0*II + c0);
  u4 a1 = *(const u4*)(Ag + (size_t)(64+r0)*II + c0);
  u4 b0 = *(const u4*)(Bg + (size_t)r0*II + c0);
  u4 b1 = *(const u4*)(Bg + (size_t)(64+r0)*II + c0);
  for (int kt = 0; kt < 32; ++kt) {
    __syncthreads();
    *(u4*)&As[r0*LDA + c0] = a0;
    *(u4*)&As[(64+r0)*LDA + c0] = a1;
    *(u4*)&Bs[r0*LDA + c0] = b0;
    *(u4*)&Bs[(64+r0)*LDA + c0] = b1;
    if (kt+1 < 32) {
      const int off = (kt+1)*32 + c0;
      a0 = *(const u4*)(Ag + (size_t)r0*II + off);
      a1 = *(const u4*)(Ag + (size_t)(64+r0)*II + off);
      b0 = *(const u4*)(Bg + (size_t)r0*II + off);
      b1 = *(const u4*)(Bg + (size_t)(64+r0)*II + off);
    }
    __syncthreads();
    h8 af[4], bf[4];
    #pragma unroll
    for (int i = 0; i < 4; ++i)
      af[i] = *(const h8*)&As[(wm*64 + i*16 + lo)*LDA + hi*8];
    #pragma unroll
    for (int j = 0; j < 4; ++j)
      bf[j] = *(const h8*)&Bs[(wn*64 + j*16 + lo)*LDA + hi*8];
    #pragma unroll
    for (int i = 0; i < 4; ++i)
      #pragma unroll
      for (int j = 0; j < 4; ++j)
        acc[i][j] = __builtin_amdgcn_mfma_f32_16x16x32_f16(af[i], bf[j], acc[i][j], 0, 0, 0);
  }
  const int nbase = bn*128 + wn*64;
  const int mbase = bm*128 + wm*64;
  #pragma unroll
  for (int j = 0; j < 4; ++j) {
    int n = nbase + j*16 + lo;
    int dir = (n >= G3_) ? 1 : 0;
    int row = n - dir*G3_;
    float bs = bias[n];
    #pragma unroll
    for (int i = 0; i < 4; ++i) {
      int m0 = mbase + i*16 + hi*4;
      #pragma unroll
      for (int v = 0; v < 4; ++v)
        gi[((size_t)dir*BT_ + (size_t)(m0+v))*G3_ + row] = (_Float16)(acc[i][j][v] + bs);
    }
  }
}

// ---------------- persistent GRU layer kernel (tagged-mailbox, clean vmcnt queues) ----------------
// 128 blocks x 512 threads. gg=bid&7: d=gg&1, g=gg>>1 (batch-chunk of 16).
// member=bid>>3 owns j-slice [member*32,+32), 3 gates of W_hh resident in LDS.
// vmcnt is PER-WAVE with IN-ORDER retirement -> a wave's wait for op X drains
// everything older. Queues kept CLEAN by role:
//   waves 0-3 (ew): ONLY mailbox LLC atomics (publish store + 16 E loads).
//   waves 4-5: MFMA only.
//   waves 6-7 (loader): gi HBM loads with REGISTER-HOLD (ds_write uses regs
//                   loaded a full step earlier), plus out stores via olds LDS
//                   handoff (256 slots: each loader thread flushes L and L+128
//                   UNCONDITIONALLY - R10's L<64 gate dropped slots 192..255).
// Mailbox protocol identical to R6/R8 (proven): 8B entries {h2|tag<<32},
// relaxed agent-scope 8B atomics; read step s: parity s&1, tag>=s+1; write:
// parity (s+1)&1, tag s+2, fire-and-forget; 2-step back-pressure; memset/launch.
#define LDW 520
__launch_bounds__(512, 1)
__global__ void gru_layer(const _Float16* __restrict__ gi,     // [dir][b*T+t][1536]
                          const _Float16* __restrict__ whh,    // layer: [dir][1536][512]
                          const float* __restrict__ bhh,       // layer: [dir][1536]
                          const float* __restrict__ h0,        // [4][64][512]
                          unsigned long long* __restrict__ tagh, // layer: [d][par][64][256] u64
                          _Float16* __restrict__ out_mid,      // layer0: [b][t][1024] fp16
                          float* __restrict__ out_fin,         // layer1: [b][t][1024] fp32
                          float* __restrict__ hn_out,          // [4][64][512] fp32
                          int layer)
{
  const int bid = blockIdx.x;
  const int gg = bid & 7, d = gg & 1, g = gg >> 1;
  const int member = bid >> 3;
  const int j0 = member * 32, b0 = g * 16;
  const int tid = threadIdx.x;
  const int wave = tid >> 6, lane = tid & 63, lo = lane & 15, hi = lane >> 4;
  const int gate = wave >> 1, jh = wave & 1;     // valid for waves 0-5

  __shared__ _Float16 wlds[3][32][LDW];
  __shared__ _Float16 hlds[16][LDW];
  __shared__ float    ghlds[3][32][17];
  __shared__ _Float16 gil[2][16][3][32];         // gi ring: [par][batch][gate][32 halves]
  __shared__ u2v      olds[256];                 // out handoff: slot = eb*16+ejp

  // --- load resident W_hh slice (512 threads, 6144 u4 chunks) ---
  const _Float16* wsrc = whh + (size_t)d*G3_*HH;
  #pragma unroll
  for (int it = 0; it < 12; ++it) {
    int idx = it*512 + tid;
    int row = idx >> 6;
    int c8 = (idx & 63) * 8;
    int gt = row >> 5, jj = row & 31;
    u4 v = *(const u4*)(wsrc + (size_t)(gt*HH + j0 + jj)*HH + c8);
    *(u4*)&wlds[gt][jj][c8] = v;
  }

  const int ejp = tid & 15;              // j-pair within slice
  const int eb  = tid >> 4;              // 0..15 batch within chunk (ew threads)
  const bool ew = (tid < 256);
  const int ejA = j0 + 2*ejp;

  unsigned long long* Tb = tagh + (size_t)d*2*BB*256;   // this direction's 2 parities

  float hj[2];
  float bhr[2], bhz[2], bhn[2];
  unsigned long long E[16];
  u4 vc0 = {}, vc1 = {};                 // loader register-hold (gi for step s+1)
  const int L = tid - 384;               // loader lane id (valid for waves 6-7)

  if (wave < 6) {
    if (ew) {
      #pragma unroll
      for (int u = 0; u < 2; ++u) {
        bhr[u] = bhh[(size_t)d*G3_ + 0*HH + ejA + u];
        bhz[u] = bhh[(size_t)d*G3_ + 1*HH + ejA + u];
        bhn[u] = bhh[(size_t)d*G3_ + 2*HH + ejA + u];
        hj[u]  = h0[((size_t)(2*layer + d)*BB + b0 + eb)*HH + ejA + u];
      }
      h2 p; p[0] = (_Float16)hj[0]; p[1] = (_Float16)hj[1];
      unsigned long long ent = (unsigned long long)__builtin_bit_cast(unsigned, p) | (1ull << 32);
      unsigned long long* ptr = Tb + (size_t)0*BB*256 + (size_t)(b0 + eb)*256 + (member*16 + ejp);
      __hip_atomic_store(ptr, ent, __ATOMIC_RELAXED, __HIP_MEMORY_SCOPE_AGENT);
      // issue E(0) (parity 0)
      #pragma unroll
      for (int q = 0; q < 4; ++q)
        #pragma unroll
        for (int k = 0; k < 4; ++k) {
          int i = tid*2 + (k >> 1);
          E[q*4+k] = __hip_atomic_load(
              Tb + (size_t)(b0 + (i >> 5))*256 + q*64 + (i & 31)*2 + (k & 1),
              __ATOMIC_RELAXED, __HIP_MEMORY_SCOPE_AGENT);
        }
    }
  } else {
    // loader prologue: gi(0) -> gil[0]; issue gi(1) -> regs
    const int t0 = d ? (TL-1) : 0;
    const int t1 = d ? (TL-2) : 1;
    {
      int seg = L >> 2, q = L & 3, gt = seg >> 4, b = seg & 15;
      u4 v = *(const u4*)(gi + (size_t)d*BT_*G3_ + ((size_t)(b0+b)*TL + t0)*(size_t)G3_ + gt*HH + j0 + q*8);
      *(u4*)&gil[0][b][gt][q*8] = v;
      vc0 = *(const u4*)(gi + (size_t)d*BT_*G3_ + ((size_t)(b0+b)*TL + t1)*(size_t)G3_ + gt*HH + j0 + q*8);
    }
    if (L < 64) {
      int i1 = L + 128;
      int seg = i1 >> 2, q = i1 & 3, gt = seg >> 4, b = seg & 15;
      u4 v = *(const u4*)(gi + (size_t)d*BT_*G3_ + ((size_t)(b0+b)*TL + t0)*(size_t)G3_ + gt*HH + j0 + q*8);
      *(u4*)&gil[0][b][gt][q*8] = v;
      vc1 = *(const u4*)(gi + (size_t)d*BT_*G3_ + ((size_t)(b0+b)*TL + t1)*(size_t)G3_ + gt*HH + j0 + q*8);
    }
  }
  __syncthreads();   // one-time full drain: wlds, gil[0], E(0) all ready

  for (int s = 0; s < TL; ++s) {
    const int t = d ? (TL-1 - s) : s;
    const int rpar = s & 1, wpar = rpar ^ 1;
    const unsigned tgt = (unsigned)(s + 1);

    if (wave < 6) {
      if (ew) {
        const unsigned long long* Trd = Tb + (size_t)rpar*BB*256;
        // --- per-lane verify + retry (queue holds ONLY LLC atomics) ---
        for (;;) {
          unsigned ok = 1u;
          #pragma unroll
          for (int k = 0; k < 16; ++k)
            ok &= (unsigned)((E[k] >> 32) >= tgt);
          if (ok) break;
          #pragma unroll
          for (int q = 0; q < 4; ++q)
            #pragma unroll
            for (int k = 0; k < 4; ++k) {
              int i = tid*2 + (k >> 1);
              E[q*4+k] = __hip_atomic_load(
                  Trd + (size_t)(b0 + (i >> 5))*256 + q*64 + (i & 31)*2 + (k & 1),
                  __ATOMIC_RELAXED, __HIP_MEMORY_SCOPE_AGENT);
            }
        }
        // --- stage all 16 entries into hlds ---
        #pragma unroll
        for (int q = 0; q < 4; ++q)
          #pragma unroll
          for (int k = 0; k < 2; ++k) {
            int i = tid*2 + k;
            int b = i >> 5, p = i & 31;
            u2v dv; dv[0] = (unsigned)E[q*4 + k*2]; dv[1] = (unsigned)E[q*4 + k*2 + 1];
            *(u2v*)&hlds[b][q*128 + p*4] = dv;
          }
      }
      asm volatile("s_waitcnt lgkmcnt(0)" ::: "memory");
      __builtin_amdgcn_s_barrier();                      // bar1
      __builtin_amdgcn_sched_barrier(0);
      // --- MFMA: (16b x 16j) per wave over K=512 ---
      f4 acc = {0.f, 0.f, 0.f, 0.f};
      #pragma unroll
      for (int kk = 0; kk < 16; ++kk) {
        h8 af = *(const h8*)&hlds[lo][kk*32 + hi*8];
        h8 bf = *(const h8*)&wlds[gate][jh*16 + lo][kk*32 + hi*8];
        acc = __builtin_amdgcn_mfma_f32_16x16x32_f16(af, bf, acc, 0, 0, 0);
      }
      #pragma unroll
      for (int v = 0; v < 4; ++v)
        ghlds[gate][jh*16 + lo][hi*4 + v] = acc[v];   // [gate][j][b]
      asm volatile("s_waitcnt lgkmcnt(0)" ::: "memory");
      __builtin_amdgcn_s_barrier();                      // bar2
      __builtin_amdgcn_sched_barrier(0);
      // --- elementwise + olds handoff + publish + issue next E ---
      if (ew) {
        unsigned giR = *(const unsigned*)&gil[rpar][eb][0][2*ejp];
        unsigned giZ = *(const unsigned*)&gil[rpar][eb][1][2*ejp];
        unsigned giN = *(const unsigned*)&gil[rpar][eb][2][2*ejp];
        h2 pR = __builtin_bit_cast(h2, giR);
        h2 pZ = __builtin_bit_cast(h2, giZ);
        h2 pN = __builtin_bit_cast(h2, giN);
        h2 hnew; float hv[2];
        #pragma unroll
        for (int u = 0; u < 2; ++u) {
          float ir = (float)pR[u], iz = (float)pZ[u], inn = (float)pN[u];
          float hr = ghlds[0][2*ejp+u][eb] + bhr[u];
          float hz = ghlds[1][2*ejp+u][eb] + bhz[u];
          float hn = ghlds[2][2*ejp+u][eb] + bhn[u];
          float rr = 1.f/(1.f + __expf(-(ir + hr)));
          float zz = 1.f/(1.f + __expf(-(iz + hz)));
          float xx = inn + rr*hn;
          float nn = 1.f - 2.f/(__expf(2.f*xx) + 1.f);   // tanh, overflow-safe
          float h  = (1.f - zz)*nn + zz*hj[u];
          hj[u] = h; hnew[u] = (_Float16)h; hv[u] = h;
        }
        unsigned hu = __builtin_bit_cast(unsigned, hnew);
        u2v ov;
        if (out_mid) { ov[0] = hu; ov[1] = hu; }
        else { ov[0] = __builtin_bit_cast(unsigned, hv[0]); ov[1] = __builtin_bit_cast(unsigned, hv[1]); }
        olds[tid] = ov;                                  // handoff to loader waves
        unsigned long long ent = (unsigned long long)hu | ((unsigned long long)(s + 2) << 32);
        unsigned long long* ptr = Tb + (size_t)wpar*BB*256 + (size_t)(b0 + eb)*256 + (member*16 + ejp);
        __hip_atomic_store(ptr, ent, __ATOMIC_RELAXED, __HIP_MEMORY_SCOPE_AGENT);
        // issue E(s+1) (parity wpar)
        const unsigned long long* Trn = Tb + (size_t)wpar*BB*256;
        #pragma unroll
        for (int q = 0; q < 4; ++q)
          #pragma unroll
          for (int k = 0; k < 4; ++k) {
            int i = tid*2 + (k >> 1);
            E[q*4+k] = __hip_atomic_load(
                Trn + (size_t)(b0 + (i >> 5))*256 + q*64 + (i & 31)*2 + (k & 1),
                __ATOMIC_RELAXED, __HIP_MEMORY_SCOPE_AGENT);
          }
      }
    } else {
      // ---------------- loader waves 6-7 ----------------
      __builtin_amdgcn_s_barrier();                      // bar1
      __builtin_amdgcn_sched_barrier(0);
      // write gil for step s+1 from regs loaded a full step ago (vmcnt wait free)
      {
        int seg = L >> 2, q = L & 3, gt = seg >> 4, b = seg & 15;
        *(u4*)&gil[wpar][b][gt][q*8] = vc0;
      }
      if (L < 64) {
        int i1 = L + 128;
        int seg = i1 >> 2, q = i1 & 3, gt = seg >> 4, b = seg & 15;
        *(u4*)&gil[wpar][b][gt][q*8] = vc1;
      }
      // issue gi(s+2) -> regs (clamped; tail value never read)
      {
        int sn = (s + 2 < TL) ? s + 2 : TL - 1;
        int tn = d ? (TL-1 - sn) : sn;
        int seg = L >> 2, q = L & 3, gt = seg >> 4, b = seg & 15;
        vc0 = *(const u4*)(gi + (size_t)d*BT_*G3_ + ((size_t)(b0+b)*TL + tn)*(size_t)G3_ + gt*HH + j0 + q*8);
        if (L < 64) {
          int i1 = L + 128;
          int seg1 = i1 >> 2, q1 = i1 & 3, gt1 = seg1 >> 4, b1 = seg1 & 15;
          vc1 = *(const u4*)(gi + (size_t)d*BT_*G3_ + ((size_t)(b0+b1)*TL + tn)*(size_t)G3_ + gt1*HH + j0 + q1*8);
        }
      }
      // out store for step s-1 (olds written end of s-1; visible since bar1).
      // 256 slots over 128 loader threads: L and L+128, BOTH unconditional.
      if (s > 0) {
        int tp = d ? (TL-1 - (s-1)) : (s-1);
        {
          int b = L >> 4, jp = L & 15;
          u2v o0 = olds[L];
          if (out_mid) *(unsigned*)(out_mid + ((size_t)(b0+b)*TL + tp)*(size_t)(2*HH) + d*HH + j0 + 2*jp) = o0[0];
          else         *(u2v*)(out_fin + ((size_t)(b0+b)*TL + tp)*(size_t)(2*HH) + d*HH + j0 + 2*jp) = o0;
        }
        {
          int i1 = L + 128;
          int b = i1 >> 4, jp = i1 & 15;
          u2v o1 = olds[i1];
          if (out_mid) *(unsigned*)(out_mid + ((size_t)(b0+b)*TL + tp)*(size_t)(2*HH) + d*HH + j0 + 2*jp) = o1[0];
          else         *(u2v*)(out_fin + ((size_t)(b0+b)*TL + tp)*(size_t)(2*HH) + d*HH + j0 + 2*jp) = o1;
        }
      }
      asm volatile("s_waitcnt lgkmcnt(0)" ::: "memory");  // gil write visible
      __builtin_amdgcn_s_barrier();                      // bar2
      __builtin_amdgcn_sched_barrier(0);
    }
  }
  // final flush: olds of step TL-1 (both slots, unconditional), hn
  asm volatile("s_waitcnt lgkmcnt(0)" ::: "memory");
  __builtin_amdgcn_s_barrier();
  __builtin_amdgcn_sched_barrier(0);
  if (wave >= 6) {
    int tp = d ? 0 : (TL-1);
    {
      int b = L >> 4, jp = L & 15;
      u2v o0 = olds[L];
      if (out_mid) *(unsigned*)(out_mid + ((size_t)(b0+b)*TL + tp)*(size_t)(2*HH) + d*HH + j0 + 2*jp) = o0[0];
      else         *(u2v*)(out_fin + ((size_t)(b0+b)*TL + tp)*(size_t)(2*HH) + d*HH + j0 + 2*jp) = o0;
    }
    {
      int i1 = L + 128;
      int b = i1 >> 4, jp = i1 & 15;
      u2v o1 = olds[i1];
      if (out_mid) *(unsigned*)(out_mid + ((size_t)(b0+b)*TL + tp)*(size_t)(2*HH) + d*HH + j0 + 2*jp) = o1[0];
      else         *(u2v*)(out_fin + ((size_t)(b0+b)*TL + tp)*(size_t)(2*HH) + d*HH + j0 + 2*jp) = o1;
    }
  }
  if (ew) {
    #pragma unroll
    for (int u = 0; u < 2; ++u)
      hn_out[((size_t)(2*layer + d)*BB + b0 + eb)*HH + ejA + u] = hj[u];
  }
}

// ---------------- host launcher ----------------
extern "C" void kernel_launch(void* const* d_in, const int* in_sizes, int n_in,
                              void* d_out, int out_size, void* d_ws, size_t ws_size,
                              hipStream_t stream) {
  (void)in_sizes; (void)n_in; (void)out_size;
  const float* x   = (const float*)d_in[0];
  const float* h0  = (const float*)d_in[1];
  const float* wih = (const float*)d_in[2];
  const float* whh = (const float*)d_in[3];
  const float* bih = (const float*)d_in[4];
  const float* bhh = (const float*)d_in[5];
  float* out = (float*)d_out;

  char* ws = (char*)d_ws;
  size_t off = 0;
  auto alloc = [&](size_t bytes) {
    char* p = ws + off;
    off += (bytes + 255) & ~(size_t)255;
    return p;
  };
  _Float16* x16   = (_Float16*)alloc((size_t)BT_*II*2);          // 128 MB
  _Float16* mid16 = (_Float16*)alloc((size_t)BT_*II*2);          // 128 MB
  _Float16* gi16  = (_Float16*)alloc((size_t)2*BT_*G3_*2);       // 384 MB
  _Float16* wih16 = (_Float16*)alloc((size_t)NL*N2_*II*2);       // 12 MB
  _Float16* whh16 = (_Float16*)alloc((size_t)NL*N2_*HH*2);       // 6 MB
  unsigned long long* tagh = (unsigned long long*)alloc((size_t)NL*2*2*BB*256*8); // 1 MB
  if (off > ws_size) {
    fprintf(stderr, "kernel_launch: workspace too small: need %zu have %zu\n", off, ws_size);
    return;
  }

  hipMemsetAsync(tagh, 0, (size_t)NL*2*2*BB*256*8, stream);      // clear stale tags (per replay)
  cvt_f2h<<<2048, 256, 0, stream>>>(x,   x16,   (size_t)BT_*II/4);
  cvt_f2h<<<512,  256, 0, stream>>>(wih, wih16, (size_t)NL*N2_*II/4);
  cvt_f2h<<<512,  256, 0, stream>>>(whh, whh16, (size_t)NL*N2_*HH/4);

  float* hn = out + (size_t)BT_*II;   // h_n region: (4,64,512) after (B,T,2H)

  // layer 0
  gemm_gi<<<dim3(24, 512), 256, 0, stream>>>(x16, wih16, bih, gi16);
  gru_layer<<<128, 512, 0, stream>>>(gi16, whh16, bhh, h0, tagh,
                                     mid16, nullptr, hn, 0);
  // layer 1
  gemm_gi<<<dim3(24, 512), 256, 0, stream>>>(mid16, wih16 + (size_t)N2_*II, bih + N2_, gi16);
  gru_layer<<<128, 512, 0, stream>>>(gi16, whh16 + (size_t)N2_*HH, bhh + N2_, h0,
                                     tagh + (size_t)2*2*BB*256, nullptr, out, hn, 1);
}

// Round 12
// 8121.564 us; speedup vs baseline: 1.1205x; 1.1205x over previous
//
#include <hip/hip_runtime.h>
#include <stdint.h>
#include <stdio.h>

// Problem constants
#define TL 1024          // T
#define BB 64            // B
#define HH 512           // H
#define II 1024          // input size (== 2H for layer 2)
#define NL 2             // layers
#define BT_ (BB*TL)      // 65536
#define G3_ 1536         // 3H
#define N2_ 3072         // 2*3H (both dirs stacked)

typedef _Float16 h8 __attribute__((ext_vector_type(8)));
typedef _Float16 h4 __attribute__((ext_vector_type(4)));
typedef _Float16 h2 __attribute__((ext_vector_type(2)));
typedef float    f4 __attribute__((ext_vector_type(4)));
typedef unsigned int u4 __attribute__((ext_vector_type(4)));
typedef unsigned int u2v __attribute__((ext_vector_type(2)));

// ---------------- fp32 -> fp16 convert ----------------
__global__ void cvt_f2h(const float* __restrict__ src, _Float16* __restrict__ dst, size_t n4) {
  size_t i = (size_t)blockIdx.x*blockDim.x + threadIdx.x;
  size_t stride = (size_t)gridDim.x*blockDim.x;
  for (; i < n4; i += stride) {
    f4 v = ((const f4*)src)[i];
    h4 o;
    o[0] = (_Float16)v[0]; o[1] = (_Float16)v[1];
    o[2] = (_Float16)v[2]; o[3] = (_Float16)v[3];
    ((h4*)dst)[i] = o;
  }
}

// ---------------- gi GEMM (unchanged, proven) ----------------
#define LDA 40
__launch_bounds__(256)
__global__ void gemm_gi(const _Float16* __restrict__ A, const _Float16* __restrict__ Bw,
                        const float* __restrict__ bias, _Float16* __restrict__ gi)
{
  const int bn = blockIdx.x, bm = blockIdx.y;
  const int tid = threadIdx.x;
  const int wave = tid >> 6, lane = tid & 63;
  const int wm = wave >> 1, wn = wave & 1;
  const int lo = lane & 15, hi = lane >> 4;
  __shared__ _Float16 As[128*LDA];
  __shared__ _Float16 Bs[128*LDA];
  f4 acc[4][4] = {};
  const int r0 = tid >> 2, c0 = (tid & 3)*8;
  const _Float16* Ag = A + (size_t)(bm*128)*II;
  const _Float16* Bg = Bw + (size_t)(bn*128)*II;
  u4 a0 = *(const u4*)(Ag + (size_t)r0*II + c0);
  u4 a1 = *(const u4*)(Ag + (size_t)(64+r0)*II + c0);
  u4 b0 = *(const u4*)(Bg + (size_t)r0*II + c0);
  u4 b1 = *(const u4*)(Bg + (size_t)(64+r0)*II + c0);
  for (int kt = 0; kt < 32; ++kt) {
    __syncthreads();
    *(u4*)&As[r0*LDA + c0] = a0;
    *(u4*)&As[(64+r0)*LDA + c0] = a1;
    *(u4*)&Bs[r0*LDA + c0] = b0;
    *(u4*)&Bs[(64+r0)*LDA + c0] = b1;
    if (kt+1 < 32) {
      const int off = (kt+1)*32 + c0;
      a0 = *(const u4*)(Ag + (size_t)r0*II + off);
      a1 = *(const u4*)(Ag + (size_t)(64+r0)*II + off);
      b0 = *(const u4*)(Bg + (size_t)r0*II + off);
      b1 = *(const u4*)(Bg + (size_t)(64+r0)*II + off);
    }
    __syncthreads();
    h8 af[4], bf[4];
    #pragma unroll
    for (int i = 0; i < 4; ++i)
      af[i] = *(const h8*)&As[(wm*64 + i*16 + lo)*LDA + hi*8];
    #pragma unroll
    for (int j = 0; j < 4; ++j)
      bf[j] = *(const h8*)&Bs[(wn*64 + j*16 + lo)*LDA + hi*8];
    #pragma unroll
    for (int i = 0; i < 4; ++i)
      #pragma unroll
      for (int j = 0; j < 4; ++j)
        acc[i][j] = __builtin_amdgcn_mfma_f32_16x16x32_f16(af[i], bf[j], acc[i][j], 0, 0, 0);
  }
  const int nbase = bn*128 + wn*64;
  const int mbase = bm*128 + wm*64;
  #pragma unroll
  for (int j = 0; j < 4; ++j) {
    int n = nbase + j*16 + lo;
    int dir = (n >= G3_) ? 1 : 0;
    int row = n - dir*G3_;
    float bs = bias[n];
    #pragma unroll
    for (int i = 0; i < 4; ++i) {
      int m0 = mbase + i*16 + hi*4;
      #pragma unroll
      for (int v = 0; v < 4; ++v)
        gi[((size_t)dir*BT_ + (size_t)(m0+v))*G3_ + row] = (_Float16)(acc[i][j][v] + bs);
    }
  }
}

// ---------------- persistent GRU layer kernel (flag-gated mailbox, no verification) ----------------
// 128 blocks x 384 threads. gg=bid&7: d=gg&1, g=gg>>1 (batch-chunk of 16).
// member=bid>>3 owns j-slice [member*32,+32), 3 gates of W_hh in LDS (96 KB).
// Publish (end of step s, producing version s+1 into buf[(s+1)&1]):
//   each ew thread: RETURNING atomic-exchange of its 4B h-slice (ack == data at
//   LLC; R3-proven primitive) -> vmcnt(0) -> s_barrier (all 256 acked) ->
//   tid0 stores flag[member]=s+2 (fire-forget). Flag visible => data visible.
// Consume (step s): wave 4 lanes<16 spin on the 16 member flags (self skipped,
//   64B total - kills the R8-R11 polling storm that saturated the LLC fabric),
//   barrier, then ONE unverified bulk read (8x 8B atomic loads/thread) -> LDS.
// Back-pressure: flags>=s+1 at step s start => every member finished step-(s-1)
//   reads => overwriting buf[(s+1)&1] (holds version s-1) is safe. Monotone
//   flags, memset per launch, no retries -> no deadlock, no livelock.
// gi: register-prefetched one step ahead AFTER the publish drain, so the bulk
//   h-read wait never drains an in-flight HBM load (vmcnt in-order lesson, R8).
#define LDW 520
__launch_bounds__(384, 1)
__global__ void gru_layer(const _Float16* __restrict__ gi,     // [dir][b*T+t][1536]
                          const _Float16* __restrict__ whh,    // layer: [dir][1536][512]
                          const float* __restrict__ bhh,       // layer: [dir][1536]
                          const float* __restrict__ h0,        // [4][64][512]
                          unsigned* __restrict__ hexch,        // layer: [d][par][64][256] u32
                          unsigned* __restrict__ flags,        // layer: [8 groups][16] u32
                          _Float16* __restrict__ out_mid,      // layer0: [b][t][1024] fp16
                          float* __restrict__ out_fin,         // layer1: [b][t][1024] fp32
                          float* __restrict__ hn_out,          // [4][64][512] fp32
                          int layer)
{
  const int bid = blockIdx.x;
  const int gg = bid & 7, d = gg & 1, g = gg >> 1;
  const int member = bid >> 3;
  const int j0 = member * 32, b0 = g * 16;
  const int tid = threadIdx.x;
  const int wave = tid >> 6, lane = tid & 63, lo = lane & 15, hi = lane >> 4;
  const int gate = wave >> 1, jh = wave & 1;     // 6 waves: 3 gates x 2 j-halves

  __shared__ _Float16 wlds[3][32][LDW];
  __shared__ _Float16 hlds[16][LDW];
  __shared__ float    ghlds[3][32][17];

  // --- load resident W_hh slice ---
  const _Float16* wsrc = whh + (size_t)d*G3_*HH;
  #pragma unroll
  for (int it = 0; it < 16; ++it) {
    int idx = it*384 + tid;
    int row = idx >> 6;
    int c8 = (idx & 63) * 8;
    int gt = row >> 5, jj = row & 31;
    u4 v = *(const u4*)(wsrc + (size_t)(gt*HH + j0 + jj)*HH + c8);
    *(u4*)&wlds[gt][jj][c8] = v;
  }

  const int ejp = tid & 15;              // j-pair within slice
  const int eb  = tid >> 4;              // 0..15 batch within chunk (ew threads)
  const bool ew = (tid < 256);
  const int ejA = j0 + 2*ejp;

  unsigned* FL = flags + gg*16;          // this group's 16 member flags (one line)

  float hj[2];
  float bhr[2], bhz[2], bhn[2];
  unsigned gR = 0, gZ = 0, gN = 0;       // gi register prefetch (for current step)

  if (ew) {
    #pragma unroll
    for (int u = 0; u < 2; ++u) {
      bhr[u] = bhh[(size_t)d*G3_ + 0*HH + ejA + u];
      bhz[u] = bhh[(size_t)d*G3_ + 1*HH + ejA + u];
      bhn[u] = bhh[(size_t)d*G3_ + 2*HH + ejA + u];
      hj[u]  = h0[((size_t)(2*layer + d)*BB + b0 + eb)*HH + ejA + u];
    }
    h2 p; p[0] = (_Float16)hj[0]; p[1] = (_Float16)hj[1];
    unsigned pu = __builtin_bit_cast(unsigned, p);
    // version 0 -> buf[0]; returning exchange: vmcnt retire == LLC ack
    unsigned* ptr = hexch + ((size_t)(0*2 + 0)*0 /*dummy*/ , ((size_t)(d*2 + 0)*BB + b0 + eb)*256 + member*16 + ejp);
    unsigned old = __hip_atomic_exchange(ptr, pu, __ATOMIC_RELAXED, __HIP_MEMORY_SCOPE_AGENT);
    asm volatile("" :: "v"(old));
    // gi(0) prefetch
    const int t0 = d ? (TL-1) : 0;
    const _Float16* pg = gi + ((size_t)d*BT_ + (size_t)(b0 + eb)*TL + t0)*(size_t)G3_ + ejA;
    gR = *(const unsigned*)(pg);
    gZ = *(const unsigned*)(pg + HH);
    gN = *(const unsigned*)(pg + 2*HH);
  }
  asm volatile("s_waitcnt vmcnt(0)" ::: "memory");
  __syncthreads();
  if (tid == 0)
    __hip_atomic_store(&FL[member], 1u, __ATOMIC_RELAXED, __HIP_MEMORY_SCOPE_AGENT);

  for (int s = 0; s < TL; ++s) {
    const int t = d ? (TL-1 - s) : s;
    const int rpar = s & 1, wpar = rpar ^ 1;
    const unsigned tgt = (unsigned)(s + 1);

    // --- spin on 16 member flags (wave 4, lanes<16; self skipped) ---
    if (wave == 4) {
      const int m = lane & 15;
      const bool act = (lane < 16) && (m != member);
      for (;;) {
        unsigned v = tgt;
        if (act) v = __hip_atomic_load(&FL[m], __ATOMIC_RELAXED, __HIP_MEMORY_SCOPE_AGENT);
        if (__ballot(v >= tgt) == ~0ull) break;
      }
    }
    __builtin_amdgcn_s_barrier();                      // bar0: flags confirmed
    __builtin_amdgcn_sched_barrier(0);
    // --- unverified bulk read of h(s) -> LDS ---
    if (ew) {
      const unsigned long long* src = (const unsigned long long*)hexch
          + (((size_t)(d*2 + rpar)*BB + b0 + eb)*256)/2 + ejp*8;
      unsigned long long Ev[8];
      #pragma unroll
      for (int k = 0; k < 8; ++k)
        Ev[k] = __hip_atomic_load(src + k, __ATOMIC_RELAXED, __HIP_MEMORY_SCOPE_AGENT);
      #pragma unroll
      for (int k2 = 0; k2 < 4; ++k2) {
        u4 v;
        v[0] = (unsigned)Ev[2*k2];     v[1] = (unsigned)(Ev[2*k2] >> 32);
        v[2] = (unsigned)Ev[2*k2 + 1]; v[3] = (unsigned)(Ev[2*k2 + 1] >> 32);
        *(u4*)&hlds[eb][ejp*32 + k2*8] = v;
      }
    }
    asm volatile("s_waitcnt lgkmcnt(0)" ::: "memory");
    __builtin_amdgcn_s_barrier();                      // bar1: hlds ready
    __builtin_amdgcn_sched_barrier(0);
    // --- MFMA: (16b x 16j) per wave over K=512 ---
    f4 acc = {0.f, 0.f, 0.f, 0.f};
    #pragma unroll
    for (int kk = 0; kk < 16; ++kk) {
      h8 af = *(const h8*)&hlds[lo][kk*32 + hi*8];
      h8 bf = *(const h8*)&wlds[gate][jh*16 + lo][kk*32 + hi*8];
      acc = __builtin_amdgcn_mfma_f32_16x16x32_f16(af, bf, acc, 0, 0, 0);
    }
    #pragma unroll
    for (int v = 0; v < 4; ++v)
      ghlds[gate][jh*16 + lo][hi*4 + v] = acc[v];   // [gate][j][b]
    asm volatile("s_waitcnt lgkmcnt(0)" ::: "memory");
    __builtin_amdgcn_s_barrier();                      // bar2: ghlds ready
    __builtin_amdgcn_sched_barrier(0);
    // --- elementwise + publish (returning exchange) + out store ---
    if (ew) {
      h2 pR = __builtin_bit_cast(h2, gR);
      h2 pZ = __builtin_bit_cast(h2, gZ);
      h2 pN = __builtin_bit_cast(h2, gN);
      h2 hnew; float hv[2];
      #pragma unroll
      for (int u = 0; u < 2; ++u) {
        float ir = (float)pR[u], iz = (float)pZ[u], inn = (float)pN[u];
        float hr = ghlds[0][2*ejp+u][eb] + bhr[u];
        float hz = ghlds[1][2*ejp+u][eb] + bhz[u];
        float hn = ghlds[2][2*ejp+u][eb] + bhn[u];
        float rr = 1.f/(1.f + __expf(-(ir + hr)));
        float zz = 1.f/(1.f + __expf(-(iz + hz)));
        float xx = inn + rr*hn;
        float nn = 1.f - 2.f/(__expf(2.f*xx) + 1.f);   // tanh, overflow-safe
        float h  = (1.f - zz)*nn + zz*hj[u];
        hj[u] = h; hnew[u] = (_Float16)h; hv[u] = h;
      }
      unsigned hu = __builtin_bit_cast(unsigned, hnew);
      unsigned* ptr = hexch + ((size_t)(d*2 + wpar)*BB + b0 + eb)*256 + member*16 + ejp;
      unsigned old = __hip_atomic_exchange(ptr, hu, __ATOMIC_RELAXED, __HIP_MEMORY_SCOPE_AGENT);
      asm volatile("" :: "v"(old));
      if (out_mid) {
        *(unsigned*)(out_mid + ((size_t)(b0+eb)*TL + t)*(size_t)(2*HH) + d*HH + ejA) = hu;
      } else {
        u2v ov; ov[0] = __builtin_bit_cast(unsigned, hv[0]); ov[1] = __builtin_bit_cast(unsigned, hv[1]);
        *(u2v*)(out_fin + ((size_t)(b0+eb)*TL + t)*(size_t)(2*HH) + d*HH + ejA) = ov;
      }
    }
    asm volatile("s_waitcnt vmcnt(0)" ::: "memory");   // all exchanges acked at LLC
    __builtin_amdgcn_s_barrier();                      // bar3: block-wide ack
    __builtin_amdgcn_sched_barrier(0);
    if (tid == 0)
      __hip_atomic_store(&FL[member], (unsigned)(s + 2), __ATOMIC_RELAXED, __HIP_MEMORY_SCOPE_AGENT);
    // gi(s+1) prefetch AFTER drain: stays alone in queue, retires under spin
    if (ew) {
      int sn = (s + 1 < TL) ? s + 1 : s;
      int tn = d ? (TL-1 - sn) : sn;
      const _Float16* pg = gi + ((size_t)d*BT_ + (size_t)(b0 + eb)*TL + tn)*(size_t)G3_ + ejA;
      gR = *(const unsigned*)(pg);
      gZ = *(const unsigned*)(pg + HH);
      gN = *(const unsigned*)(pg + 2*HH);
    }
  }
  if (ew) {
    #pragma unroll
    for (int u = 0; u < 2; ++u)
      hn_out[((size_t)(2*layer + d)*BB + b0 + eb)*HH + ejA + u] = hj[u];
  }
}

// ---------------- host launcher ----------------
extern "C" void kernel_launch(void* const* d_in, const int* in_sizes, int n_in,
                              void* d_out, int out_size, void* d_ws, size_t ws_size,
                              hipStream_t stream) {
  (void)in_sizes; (void)n_in; (void)out_size;
  const float* x   = (const float*)d_in[0];
  const float* h0  = (const float*)d_in[1];
  const float* wih = (const float*)d_in[2];
  const float* whh = (const float*)d_in[3];
  const float* bih = (const float*)d_in[4];
  const float* bhh = (const float*)d_in[5];
  float* out = (float*)d_out;

  char* ws = (char*)d_ws;
  size_t off = 0;
  auto alloc = [&](size_t bytes) {
    char* p = ws + off;
    off += (bytes + 255) & ~(size_t)255;
    return p;
  };
  _Float16* x16   = (_Float16*)alloc((size_t)BT_*II*2);          // 128 MB
  _Float16* mid16 = (_Float16*)alloc((size_t)BT_*II*2);          // 128 MB
  _Float16* gi16  = (_Float16*)alloc((size_t)2*BT_*G3_*2);       // 384 MB
  _Float16* wih16 = (_Float16*)alloc((size_t)NL*N2_*II*2);       // 12 MB
  _Float16* whh16 = (_Float16*)alloc((size_t)NL*N2_*HH*2);       // 6 MB
  unsigned* hexch = (unsigned*)alloc((size_t)NL*2*2*BB*256*4);   // 512 KB data mailboxes
  unsigned* flags = (unsigned*)alloc((size_t)NL*8*16*4);         // 1 KB flags
  if (off > ws_size) {
    fprintf(stderr, "kernel_launch: workspace too small: need %zu have %zu\n", off, ws_size);
    return;
  }

  hipMemsetAsync(flags, 0, (size_t)NL*8*16*4, stream);           // clear flags (per replay)
  cvt_f2h<<<2048, 256, 0, stream>>>(x,   x16,   (size_t)BT_*II/4);
  cvt_f2h<<<512,  256, 0, stream>>>(wih, wih16, (size_t)NL*N2_*II/4);
  cvt_f2h<<<512,  256, 0, stream>>>(whh, whh16, (size_t)NL*N2_*HH/4);

  float* hn = out + (size_t)BT_*II;   // h_n region: (4,64,512) after (B,T,2H)

  // layer 0
  gemm_gi<<<dim3(24, 512), 256, 0, stream>>>(x16, wih16, bih, gi16);
  gru_layer<<<128, 384, 0, stream>>>(gi16, whh16, bhh, h0, hexch, flags,
                                     mid16, nullptr, hn, 0);
  // layer 1
  gemm_gi<<<dim3(24, 512), 256, 0, stream>>>(mid16, wih16 + (size_t)N2_*II, bih + N2_, gi16);
  gru_layer<<<128, 384, 0, stream>>>(gi16, whh16 + (size_t)N2_*HH, bhh + N2_, h0,
                                     hexch + (size_t)2*2*BB*256, flags + 8*16,
                                     nullptr, out, hn, 1);
}